// Round 7
// baseline (683.894 us; speedup 1.0000x reference)
//
#include <hip/hip_runtime.h>
#include <hip/hip_bf16.h>

// Problem constants
#define B_ 4
#define T_ 2048
#define E_ 1024
#define H_ 16
#define D_ 64
#define M_ (B_ * T_)  // 8192 rows

typedef unsigned short u16;
typedef short s16x8 __attribute__((ext_vector_type(8)));
typedef unsigned short u16x8 __attribute__((ext_vector_type(8)));
typedef float f32x4 __attribute__((ext_vector_type(4)));

__device__ __forceinline__ u16 f2bf(float f) {
    __hip_bfloat16 h = __float2bfloat16(f);
    return __builtin_bit_cast(u16, h);
}
__device__ __forceinline__ float bf2f(u16 u) {
    unsigned int v = ((unsigned int)u) << 16;
    return __builtin_bit_cast(float, v);
}

// ---------------------------------------------------------------------------
// Dtype probe (block-cooperative, 256 threads). Deterministic across blocks.
// Verified behaviorally: inputs are bf16 (rounds 2-6 agree); fp32 path kept
// for robustness.
// ---------------------------------------------------------------------------
__device__ __forceinline__ int block_probe_is_bf16(const void* x, int tid) {
    const u16* p = (const u16*)x;
    u16 u = p[tid];
    int e = (u >> 7) & 0xFF;
    int ok = ((u & 0x7FFF) == 0 || (e >= 103 && e <= 133)) ? 1 : 0;
    return (__syncthreads_count(ok) >= 240) ? 1 : 0;
}

// ---------------------------------------------------------------------------
// Split transpose for Wq,Wk: W[k][n](fp32 or bf16) -> hi[n][k], lo[n][k] bf16
// ---------------------------------------------------------------------------
__global__ __launch_bounds__(256) void transpose_w_split_kernel(
    const void* __restrict__ w0, const void* __restrict__ w1,
    u16* __restrict__ hi0, u16* __restrict__ lo0,
    u16* __restrict__ hi1, u16* __restrict__ lo1,
    const void* __restrict__ xprobe)
{
    __shared__ u16 th[64][66], tl[64][66];
    const int x = threadIdx.x, y = threadIdx.y;
    const int isbf = block_probe_is_bf16(xprobe, y * 64 + x);
    const void* in = blockIdx.z ? w1 : w0;
    u16* ho = blockIdx.z ? hi1 : hi0;
    u16* lo = blockIdx.z ? lo1 : lo0;
    const int r0 = blockIdx.y * 64;  // k
    const int c0 = blockIdx.x * 64;  // n
    #pragma unroll
    for (int j = 0; j < 16; j++) {
        const size_t idx = (size_t)(r0 + y * 16 + j) * E_ + c0 + x;
        float v = isbf ? bf2f(((const u16*)in)[idx]) : ((const float*)in)[idx];
        u16 h = f2bf(v);
        th[y * 16 + j][x] = h;
        tl[y * 16 + j][x] = f2bf(v - bf2f(h));
    }
    __syncthreads();
    #pragma unroll
    for (int j = 0; j < 16; j++) {
        ho[(size_t)(c0 + y * 16 + j) * E_ + r0 + x] = th[x][y * 16 + j];
        lo[(size_t)(c0 + y * 16 + j) * E_ + r0 + x] = tl[x][y * 16 + j];
    }
}

// ---------------------------------------------------------------------------
// Single-precision (bf16) transpose for Wv,Wo
// ---------------------------------------------------------------------------
__global__ __launch_bounds__(256) void transpose_w_single_kernel(
    const void* __restrict__ w0, const void* __restrict__ w1,
    u16* __restrict__ o0, u16* __restrict__ o1,
    const void* __restrict__ xprobe)
{
    __shared__ u16 th[64][66];
    const int x = threadIdx.x, y = threadIdx.y;
    const int isbf = block_probe_is_bf16(xprobe, y * 64 + x);
    const void* in = blockIdx.z ? w1 : w0;
    u16* o = blockIdx.z ? o1 : o0;
    const int r0 = blockIdx.y * 64;
    const int c0 = blockIdx.x * 64;
    #pragma unroll
    for (int j = 0; j < 16; j++) {
        const size_t idx = (size_t)(r0 + y * 16 + j) * E_ + c0 + x;
        float v = isbf ? bf2f(((const u16*)in)[idx]) : ((const float*)in)[idx];
        th[y * 16 + j][x] = f2bf(v);
    }
    __syncthreads();
    #pragma unroll
    for (int j = 0; j < 16; j++)
        o[(size_t)(c0 + y * 16 + j) * E_ + r0 + x] = th[x][y * 16 + j];
}

// ---------------------------------------------------------------------------
// Biases: q,k -> fp32; v,o -> bf16
// ---------------------------------------------------------------------------
__global__ __launch_bounds__(256) void convert_bias_kernel(
    const void* __restrict__ bq, const void* __restrict__ bk,
    const void* __restrict__ bv, const void* __restrict__ bo,
    float* __restrict__ bqf, float* __restrict__ bkf,
    u16* __restrict__ bvb, u16* __restrict__ bob,
    const void* __restrict__ xprobe)
{
    const int isbf = block_probe_is_bf16(xprobe, threadIdx.x);
    const int i = blockIdx.x * 256 + threadIdx.x;  // < 1024
    const int w = blockIdx.y;
    const void* p = (w == 0) ? bq : (w == 1) ? bk : (w == 2) ? bv : bo;
    float v = isbf ? bf2f(((const u16*)p)[i]) : ((const float*)p)[i];
    if (w == 0) bqf[i] = v;
    else if (w == 1) bkf[i] = v;
    else if (w == 2) bvb[i] = f2bf(v);
    else bob[i] = f2bf(v);
}

// ---------------------------------------------------------------------------
// Split GEMM (fp32-accurate on bf16 MFMA): C = (Xhi+Xlo)@(Bhi+Blo)^T + bias
// (for bf16 inputs lo==0 and this equals the plain GEMM exactly).
// 128x128 tile, BK=32. Output fp32 rows 0..4095 of tmp.
// ---------------------------------------------------------------------------
__global__ __launch_bounds__(256) void gemm_split_kernel(
    const void* __restrict__ X, int m_base,
    const u16* __restrict__ Bhi, const u16* __restrict__ Blo,
    const float* __restrict__ bias, float* __restrict__ Cout)
{
    __shared__ u16 ah_lds[128 * 40], al_lds[128 * 40];
    __shared__ u16 bh_lds[128 * 40], bl_lds[128 * 40];
    const int tid = threadIdx.x;
    const int isbf = block_probe_is_bf16(X, tid);
    const int wave = tid >> 6, lane = tid & 63;
    const int lane15 = lane & 15, quad = lane >> 4;
    const int wm = (wave & 1) * 64, wn = (wave >> 1) * 64;
    const int m0 = blockIdx.y * 128, n0 = blockIdx.x * 128;
    const int srow = tid >> 1;
    const int soff = (tid & 1) * 16;

    f32x4 acc[4][4];
    #pragma unroll
    for (int i = 0; i < 4; i++)
        #pragma unroll
        for (int j = 0; j < 4; j++) acc[i][j] = (f32x4)0.0f;

    for (int kk = 0; kk < E_; kk += 32) {
        float va[16];
        if (isbf) {
            const u16* xa = (const u16*)X + (size_t)(m_base + m0 + srow) * E_ + kk + soff;
            u16x8 t0 = *(const u16x8*)xa, t1 = *(const u16x8*)(xa + 8);
            #pragma unroll
            for (int j = 0; j < 8; j++) { va[j] = bf2f(t0[j]); va[8 + j] = bf2f(t1[j]); }
        } else {
            const float* xa = (const float*)X + (size_t)(m_base + m0 + srow) * E_ + kk + soff;
            #pragma unroll
            for (int j = 0; j < 16; j += 4) {
                f32x4 t = *(const f32x4*)(xa + j);
                va[j] = t[0]; va[j + 1] = t[1]; va[j + 2] = t[2]; va[j + 3] = t[3];
            }
        }
        u16x8 ah0, ah1, al0, al1;
        #pragma unroll
        for (int j = 0; j < 8; j++) {
            u16 h = f2bf(va[j]);
            ah0[j] = h; al0[j] = f2bf(va[j] - bf2f(h));
            u16 h2 = f2bf(va[8 + j]);
            ah1[j] = h2; al1[j] = f2bf(va[8 + j] - bf2f(h2));
        }
        const u16* bhp = Bhi + (size_t)(n0 + srow) * E_ + kk + soff;
        const u16* blp = Blo + (size_t)(n0 + srow) * E_ + kk + soff;
        u16x8 bh0 = *(const u16x8*)bhp, bh1 = *(const u16x8*)(bhp + 8);
        u16x8 bl0 = *(const u16x8*)blp, bl1 = *(const u16x8*)(blp + 8);

        __syncthreads();
        *(u16x8*)&ah_lds[srow * 40 + soff] = ah0;
        *(u16x8*)&ah_lds[srow * 40 + soff + 8] = ah1;
        *(u16x8*)&al_lds[srow * 40 + soff] = al0;
        *(u16x8*)&al_lds[srow * 40 + soff + 8] = al1;
        *(u16x8*)&bh_lds[srow * 40 + soff] = bh0;
        *(u16x8*)&bh_lds[srow * 40 + soff + 8] = bh1;
        *(u16x8*)&bl_lds[srow * 40 + soff] = bl0;
        *(u16x8*)&bl_lds[srow * 40 + soff + 8] = bl1;
        __syncthreads();

        s16x8 afh[4], afl[4], bfh[4], bfl[4];
        #pragma unroll
        for (int i = 0; i < 4; i++) {
            afh[i] = *(const s16x8*)&ah_lds[(wm + i * 16 + lane15) * 40 + quad * 8];
            afl[i] = *(const s16x8*)&al_lds[(wm + i * 16 + lane15) * 40 + quad * 8];
        }
        #pragma unroll
        for (int j = 0; j < 4; j++) {
            bfh[j] = *(const s16x8*)&bh_lds[(wn + j * 16 + lane15) * 40 + quad * 8];
            bfl[j] = *(const s16x8*)&bl_lds[(wn + j * 16 + lane15) * 40 + quad * 8];
        }
        #pragma unroll
        for (int i = 0; i < 4; i++) {
            #pragma unroll
            for (int j = 0; j < 4; j++) {
                acc[i][j] = __builtin_amdgcn_mfma_f32_16x16x32_bf16(afh[i], bfh[j], acc[i][j], 0, 0, 0);
                acc[i][j] = __builtin_amdgcn_mfma_f32_16x16x32_bf16(afh[i], bfl[j], acc[i][j], 0, 0, 0);
                acc[i][j] = __builtin_amdgcn_mfma_f32_16x16x32_bf16(afl[i], bfh[j], acc[i][j], 0, 0, 0);
            }
        }
    }

    #pragma unroll
    for (int j = 0; j < 4; j++) {
        const int col = n0 + wn + j * 16 + lane15;
        const float bb = bias[col];
        #pragma unroll
        for (int i = 0; i < 4; i++) {
            const int row = m0 + wm + i * 16 + quad * 4;
            #pragma unroll
            for (int r = 0; r < 4; r++)
                Cout[(size_t)(row + r) * E_ + col] = acc[i][j][r] + bb;
        }
    }
}

// ---------------------------------------------------------------------------
// V projection (bf16, A from original X) with FUSED per-head transpose:
// writes vt[(b*16+h)*64+d][t] directly via an LDS retile in the epilogue.
// ---------------------------------------------------------------------------
__global__ __launch_bounds__(256) void gemm_v_fused_kernel(
    const void* __restrict__ X, const u16* __restrict__ Bt,
    const u16* __restrict__ bias, u16* __restrict__ Vt)
{
    __shared__ u16 smem[2 * 128 * 72];  // a | b, later c_tile[128][132]
    u16* a_lds = smem;
    u16* b_lds = smem + 128 * 72;
    const int tid = threadIdx.x;
    const int isbf = block_probe_is_bf16(X, tid);
    const int wave = tid >> 6, lane = tid & 63;
    const int lane15 = lane & 15, quad = lane >> 4;
    const int wm = (wave & 1) * 64, wn = (wave >> 1) * 64;
    const int m0 = blockIdx.y * 128, n0 = blockIdx.x * 128;
    const int srow = tid >> 1;
    const int soff = (tid & 1) * 32;

    f32x4 acc[4][4];
    #pragma unroll
    for (int i = 0; i < 4; i++)
        #pragma unroll
        for (int j = 0; j < 4; j++) acc[i][j] = (f32x4)0.0f;

    for (int kk = 0; kk < E_; kk += 64) {
        u16x8 av[4];
        if (isbf) {
            const u16* xa = (const u16*)X + (size_t)(m0 + srow) * E_ + kk + soff;
            #pragma unroll
            for (int j = 0; j < 4; j++) av[j] = *(const u16x8*)(xa + j * 8);
        } else {
            const float* xa = (const float*)X + (size_t)(m0 + srow) * E_ + kk + soff;
            #pragma unroll
            for (int j = 0; j < 4; j++) {
                f32x4 t0 = *(const f32x4*)(xa + j * 8);
                f32x4 t1 = *(const f32x4*)(xa + j * 8 + 4);
                u16x8 o;
                #pragma unroll
                for (int e = 0; e < 4; e++) { o[e] = f2bf(t0[e]); o[4 + e] = f2bf(t1[e]); }
                av[j] = o;
            }
        }
        const u16* bp = Bt + (size_t)(n0 + srow) * E_ + kk + soff;
        u16x8 bv[4];
        #pragma unroll
        for (int j = 0; j < 4; j++) bv[j] = *(const u16x8*)(bp + j * 8);

        __syncthreads();
        #pragma unroll
        for (int j = 0; j < 4; j++) {
            *(u16x8*)&a_lds[srow * 72 + soff + j * 8] = av[j];
            *(u16x8*)&b_lds[srow * 72 + soff + j * 8] = bv[j];
        }
        __syncthreads();
        #pragma unroll
        for (int ks = 0; ks < 2; ks++) {
            s16x8 af[4], bfr[4];
            #pragma unroll
            for (int i = 0; i < 4; i++)
                af[i] = *(const s16x8*)&a_lds[(wm + i * 16 + lane15) * 72 + ks * 32 + quad * 8];
            #pragma unroll
            for (int j = 0; j < 4; j++)
                bfr[j] = *(const s16x8*)&b_lds[(wn + j * 16 + lane15) * 72 + ks * 32 + quad * 8];
            #pragma unroll
            for (int i = 0; i < 4; i++)
                #pragma unroll
                for (int j = 0; j < 4; j++)
                    acc[i][j] = __builtin_amdgcn_mfma_f32_16x16x32_bf16(af[i], bfr[j], acc[i][j], 0, 0, 0);
        }
    }

    // epilogue: C tile -> LDS -> transposed coalesced store into Vt
    __syncthreads();  // all waves done with a/b LDS
    u16* c_tile = smem;  // [128][132]
    #pragma unroll
    for (int j = 0; j < 4; j++) {
        const float bb = bf2f(bias[n0 + wn + j * 16 + lane15]);
        #pragma unroll
        for (int i = 0; i < 4; i++)
            #pragma unroll
            for (int r = 0; r < 4; r++)
                c_tile[(wm + i * 16 + quad * 4 + r) * 132 + wn + j * 16 + lane15] =
                    f2bf(acc[i][j][r] + bb);
    }
    __syncthreads();
    const int b = m0 >> 11, t0 = m0 & 2047;
    const int orow = tid >> 1, half = tid & 1;
    u16* dst = Vt + ((size_t)b * 1024 + n0 + orow) * T_ + t0 + half * 64;
    #pragma unroll
    for (int c = 0; c < 8; c++) {
        u16x8 o;
        #pragma unroll
        for (int e = 0; e < 8; e++)
            o[e] = c_tile[(half * 64 + c * 8 + e) * 132 + orow];
        *(u16x8*)(dst + c * 8) = o;
    }
}

// ---------------------------------------------------------------------------
// Plain bf16 GEMM + bias — final output projection. OUT fP32 (d_out dtype!).
// ---------------------------------------------------------------------------
__global__ __launch_bounds__(256) void gemm_out_kernel(
    const u16* __restrict__ A, const u16* __restrict__ Bt,
    const u16* __restrict__ bias, float* __restrict__ Cout)
{
    __shared__ u16 a_lds[128 * 72];
    __shared__ u16 b_lds[128 * 72];
    const int tid = threadIdx.x;
    const int wave = tid >> 6, lane = tid & 63;
    const int lane15 = lane & 15, quad = lane >> 4;
    const int wm = (wave & 1) * 64, wn = (wave >> 1) * 64;
    const int m0 = blockIdx.y * 128, n0 = blockIdx.x * 128;
    const int srow = tid >> 1;
    const int soff = (tid & 1) * 32;

    const u16* aptr = A + (size_t)(m0 + srow) * E_ + soff;
    const u16* bptr = Bt + (size_t)(n0 + srow) * E_ + soff;

    f32x4 acc[4][4];
    #pragma unroll
    for (int i = 0; i < 4; i++)
        #pragma unroll
        for (int j = 0; j < 4; j++) acc[i][j] = (f32x4)0.0f;

    for (int kk = 0; kk < E_; kk += 64) {
        s16x8 av[4], bv[4];
        #pragma unroll
        for (int j = 0; j < 4; j++) {
            av[j] = *(const s16x8*)(aptr + kk + j * 8);
            bv[j] = *(const s16x8*)(bptr + kk + j * 8);
        }
        __syncthreads();
        #pragma unroll
        for (int j = 0; j < 4; j++) {
            *(s16x8*)&a_lds[srow * 72 + soff + j * 8] = av[j];
            *(s16x8*)&b_lds[srow * 72 + soff + j * 8] = bv[j];
        }
        __syncthreads();
        #pragma unroll
        for (int ks = 0; ks < 2; ks++) {
            s16x8 af[4], bfr[4];
            #pragma unroll
            for (int i = 0; i < 4; i++)
                af[i] = *(const s16x8*)&a_lds[(wm + i * 16 + lane15) * 72 + ks * 32 + quad * 8];
            #pragma unroll
            for (int j = 0; j < 4; j++)
                bfr[j] = *(const s16x8*)&b_lds[(wn + j * 16 + lane15) * 72 + ks * 32 + quad * 8];
            #pragma unroll
            for (int i = 0; i < 4; i++)
                #pragma unroll
                for (int j = 0; j < 4; j++)
                    acc[i][j] = __builtin_amdgcn_mfma_f32_16x16x32_bf16(af[i], bfr[j], acc[i][j], 0, 0, 0);
        }
    }

    #pragma unroll
    for (int j = 0; j < 4; j++) {
        const int col = n0 + wn + j * 16 + lane15;
        const float bb = bf2f(bias[col]);
        #pragma unroll
        for (int i = 0; i < 4; i++) {
            const int row = m0 + wm + i * 16 + quad * 4;
            #pragma unroll
            for (int r = 0; r < 4; r++)
                Cout[(size_t)(row + r) * E_ + col] = acc[i][j][r] + bb;  // fp32!
        }
    }
}

// ---------------------------------------------------------------------------
// quantum_layer: out[row][:] = cumprod(cos(in[row][:])), 1024 features.
// ---------------------------------------------------------------------------
__global__ __launch_bounds__(256) void quantum_kernel(
    const float* __restrict__ in, u16* __restrict__ out)
{
    const int wave = threadIdx.x >> 6, lane = threadIdx.x & 63;
    const size_t row = (size_t)blockIdx.x * 4 + wave;
    const float* p = in + row * E_ + lane * 16;
    float v[16];
    #pragma unroll
    for (int j = 0; j < 16; j += 4) {
        f32x4 t = *(const f32x4*)(p + j);
        v[j] = t[0]; v[j + 1] = t[1]; v[j + 2] = t[2]; v[j + 3] = t[3];
    }
    float pl[16];
    float run = 1.0f;
    #pragma unroll
    for (int j = 0; j < 16; j++) { run *= cosf(v[j]); pl[j] = run; }
    float incl = run;
    #pragma unroll
    for (int off = 1; off < 64; off <<= 1) {
        float t = __shfl_up(incl, off);
        if (lane >= off) incl *= t;
    }
    float pref = __shfl_up(incl, 1);
    if (lane == 0) pref = 1.0f;
    u16x8 o0, o1;
    #pragma unroll
    for (int j = 0; j < 8; j++) {
        o0[j] = f2bf(pref * pl[j]);
        o1[j] = f2bf(pref * pl[j + 8]);
    }
    *(u16x8*)(out + row * E_ + lane * 16) = o0;
    *(u16x8*)(out + row * E_ + lane * 16 + 8) = o1;
}

// ---------------------------------------------------------------------------
// MFMA flash attention per (b,h): Q-tile 128 rows, K/V chunks of 64.
// Cross-validated bitwise (to bf16) against the independent VALU implementation
// in rounds 2/4/5.
// ---------------------------------------------------------------------------
__global__ __launch_bounds__(256) void attn_kernel(
    const u16* __restrict__ Qrm, const u16* __restrict__ Krm,
    const u16* __restrict__ Vt, u16* __restrict__ Orm)
{
    __shared__ u16 q_lds[128 * 72];
    __shared__ u16 kp_lds[128 * 72];
    __shared__ u16 v_lds[64 * 72];
    const int tid = threadIdx.x;
    const int wave = tid >> 6, lane = tid & 63;
    const int lane15 = lane & 15, quad = lane >> 4;
    const int bh = blockIdx.y;
    const int b = bh >> 4, h = bh & 15;
    const int t0 = blockIdx.x * 128;

    {
        const int srow = tid >> 1;
        const int soff = (tid & 1) * 32;
        const u16* src = Qrm + (size_t)(b * T_ + t0 + srow) * E_ + h * 64 + soff;
        #pragma unroll
        for (int j = 0; j < 4; j++)
            *(s16x8*)&q_lds[srow * 72 + soff + j * 8] = *(const s16x8*)(src + j * 8);
    }

    float m_i[2][4], l_i[2][4];
    f32x4 oacc[2][4];
    #pragma unroll
    for (int mt = 0; mt < 2; mt++) {
        #pragma unroll
        for (int r = 0; r < 4; r++) { m_i[mt][r] = -__builtin_inff(); l_i[mt][r] = 0.0f; }
        #pragma unroll
        for (int n = 0; n < 4; n++) oacc[mt][n] = (f32x4)0.0f;
    }

    const u16* kbase = Krm + (size_t)(b * T_) * E_ + h * 64;
    const u16* vbase = Vt + (size_t)bh * 64 * T_;

    for (int tk0 = 0; tk0 < T_; tk0 += 64) {
        __syncthreads();
        {
            const int srow = tid >> 2;
            const int soff = (tid & 3) * 16;
            const u16* ksrc = kbase + (size_t)(tk0 + srow) * E_ + soff;
            *(s16x8*)&kp_lds[srow * 72 + soff]     = *(const s16x8*)(ksrc);
            *(s16x8*)&kp_lds[srow * 72 + soff + 8] = *(const s16x8*)(ksrc + 8);
            const u16* vsrc = vbase + (size_t)srow * T_ + tk0 + soff;
            *(s16x8*)&v_lds[srow * 72 + soff]     = *(const s16x8*)(vsrc);
            *(s16x8*)&v_lds[srow * 72 + soff + 8] = *(const s16x8*)(vsrc + 8);
        }
        __syncthreads();

        f32x4 sacc[2][4];
        #pragma unroll
        for (int mt = 0; mt < 2; mt++)
            #pragma unroll
            for (int j = 0; j < 4; j++) sacc[mt][j] = (f32x4)0.0f;
        #pragma unroll
        for (int ks = 0; ks < 2; ks++) {
            s16x8 qa[2], kb[4];
            #pragma unroll
            for (int mt = 0; mt < 2; mt++)
                qa[mt] = *(const s16x8*)&q_lds[(wave * 32 + mt * 16 + lane15) * 72 + ks * 32 + quad * 8];
            #pragma unroll
            for (int j = 0; j < 4; j++)
                kb[j] = *(const s16x8*)&kp_lds[(j * 16 + lane15) * 72 + ks * 32 + quad * 8];
            #pragma unroll
            for (int mt = 0; mt < 2; mt++)
                #pragma unroll
                for (int j = 0; j < 4; j++)
                    sacc[mt][j] = __builtin_amdgcn_mfma_f32_16x16x32_bf16(
                        qa[mt], kb[j], sacc[mt][j], 0, 0, 0);
        }

        float mrow[2][4], alpha[2][4];
        #pragma unroll
        for (int mt = 0; mt < 2; mt++) {
            #pragma unroll
            for (int r = 0; r < 4; r++) {
                float mx = fmaxf(fmaxf(sacc[mt][0][r], sacc[mt][1][r]),
                                 fmaxf(sacc[mt][2][r], sacc[mt][3][r]));
                mx *= 0.125f;
                #pragma unroll
                for (int d = 1; d < 16; d <<= 1)
                    mx = fmaxf(mx, __shfl_xor(mx, d));
                const float mn = fmaxf(m_i[mt][r], mx);
                alpha[mt][r] = __expf(m_i[mt][r] - mn);
                m_i[mt][r] = mn;
                mrow[mt][r] = mn;
            }
        }
        #pragma unroll
        for (int mt = 0; mt < 2; mt++) {
            #pragma unroll
            for (int r = 0; r < 4; r++) {
                float s = 0.0f;
                #pragma unroll
                for (int j = 0; j < 4; j++) {
                    const float pv = __expf(sacc[mt][j][r] * 0.125f - mrow[mt][r]);
                    sacc[mt][j][r] = pv;
                    s += pv;
                }
                #pragma unroll
                for (int d = 1; d < 16; d <<= 1)
                    s += __shfl_xor(s, d);
                l_i[mt][r] = l_i[mt][r] * alpha[mt][r] + s;
                #pragma unroll
                for (int n = 0; n < 4; n++)
                    oacc[mt][n][r] *= alpha[mt][r];
            }
        }

        __syncthreads();

        #pragma unroll
        for (int mt = 0; mt < 2; mt++)
            #pragma unroll
            for (int j = 0; j < 4; j++)
                #pragma unroll
                for (int r = 0; r < 4; r++)
                    kp_lds[(wave * 32 + mt * 16 + quad * 4 + r) * 72 + j * 16 + lane15] =
                        f2bf(sacc[mt][j][r]);

        #pragma unroll
        for (int ks = 0; ks < 2; ks++) {
            s16x8 pa[2], vb[4];
            #pragma unroll
            for (int mt = 0; mt < 2; mt++)
                pa[mt] = *(const s16x8*)&kp_lds[(wave * 32 + mt * 16 + lane15) * 72 + ks * 32 + quad * 8];
            #pragma unroll
            for (int n = 0; n < 4; n++)
                vb[n] = *(const s16x8*)&v_lds[(n * 16 + lane15) * 72 + ks * 32 + quad * 8];
            #pragma unroll
            for (int mt = 0; mt < 2; mt++)
                #pragma unroll
                for (int n = 0; n < 4; n++)
                    oacc[mt][n] = __builtin_amdgcn_mfma_f32_16x16x32_bf16(
                        pa[mt], vb[n], oacc[mt][n], 0, 0, 0);
        }
    }

    #pragma unroll
    for (int mt = 0; mt < 2; mt++) {
        #pragma unroll
        for (int r = 0; r < 4; r++) {
            const float inv = 1.0f / l_i[mt][r];
            const size_t row = (size_t)(b * T_ + t0 + wave * 32 + mt * 16 + quad * 4 + r);
            #pragma unroll
            for (int n = 0; n < 4; n++)
                Orm[row * E_ + h * 64 + n * 16 + lane15] = f2bf(oacc[mt][n][r] * inv);
        }
    }
}

// ---------------------------------------------------------------------------
// Workspace layout, peak 77 MiB (known-safe):
//   [0, 2M)   wt_o            [2M,+12K) biases (bqf,bkf fp32; bvb,bob bf16)
//   [3M, 5M)  wt_q_hi  [5M,7M) wt_q_lo  [7M,9M) wt_k_hi  [9M,11M) wt_k_lo
//   [11M,13M) wt_v
//   [13M,29M) vt  (per-head transposed V)
//   [29M,45M) key = quantum(q_proj)   (attention KEY)
//   [45M,61M) qry = quantum(k_proj)   (attention QUERY)
//   [61M,77M) tmp (fp32, 4096 rows) -> later orm (bf16, 8192 rows)
// ---------------------------------------------------------------------------
extern "C" void kernel_launch(void* const* d_in, const int* in_sizes, int n_in,
                              void* d_out, int out_size, void* d_ws, size_t ws_size,
                              hipStream_t stream) {
    (void)in_sizes; (void)n_in; (void)out_size; (void)ws_size;
    const void* x  = d_in[0];
    const void* Wq = d_in[1];
    const void* bq = d_in[2];
    const void* Wk = d_in[3];
    const void* bk = d_in[4];
    const void* Wv = d_in[5];
    const void* bv = d_in[6];
    const void* Wo = d_in[7];
    const void* bo = d_in[8];

    char* ws = (char*)d_ws;
    const size_t MB = 1024 * 1024;
    u16*   wt_o  = (u16*)(ws);
    float* bqf   = (float*)(ws + 2 * MB);
    float* bkf   = (float*)(ws + 2 * MB + 4096);
    u16*   bvb   = (u16*)(ws + 2 * MB + 8192);
    u16*   bob   = (u16*)(ws + 2 * MB + 10240);
    u16*   wt_qh = (u16*)(ws + 3 * MB);
    u16*   wt_ql = (u16*)(ws + 5 * MB);
    u16*   wt_kh = (u16*)(ws + 7 * MB);
    u16*   wt_kl = (u16*)(ws + 9 * MB);
    u16*   wt_v  = (u16*)(ws + 11 * MB);
    u16*   vt    = (u16*)(ws + 13 * MB);
    u16*   key   = (u16*)(ws + 29 * MB);
    u16*   qry   = (u16*)(ws + 45 * MB);
    float* tmp   = (float*)(ws + 61 * MB);
    u16*   orm   = (u16*)(ws + 61 * MB);

    transpose_w_split_kernel<<<dim3(16, 16, 2), dim3(64, 4), 0, stream>>>(
        Wq, Wk, wt_qh, wt_ql, wt_kh, wt_kl, x);
    transpose_w_single_kernel<<<dim3(16, 16, 2), dim3(64, 4), 0, stream>>>(
        Wv, Wo, wt_v, wt_o, x);
    convert_bias_kernel<<<dim3(4, 4), 256, 0, stream>>>(
        bq, bk, bv, bo, bqf, bkf, bvb, bob, x);

    // V projection with fused per-head transpose -> vt
    gemm_v_fused_kernel<<<dim3(8, 64), 256, 0, stream>>>(x, wt_v, bvb, vt);

    // q-projection -> quantum -> key  (reference: KEY = quantum(x@Wq+bq))
    for (int hh = 0; hh < 2; hh++) {
        gemm_split_kernel<<<dim3(8, 32), 256, 0, stream>>>(
            x, hh * 4096, wt_qh, wt_ql, bqf, tmp);
        quantum_kernel<<<1024, 256, 0, stream>>>(tmp, key + (size_t)hh * 4096 * E_);
    }
    // k-projection -> quantum -> qry  (reference: QUERY = quantum(x@Wk+bk))
    for (int hh = 0; hh < 2; hh++) {
        gemm_split_kernel<<<dim3(8, 32), 256, 0, stream>>>(
            x, hh * 4096, wt_kh, wt_kl, bkf, tmp);
        quantum_kernel<<<1024, 256, 0, stream>>>(tmp, qry + (size_t)hh * 4096 * E_);
    }

    attn_kernel<<<dim3(16, 64), 256, 0, stream>>>(qry, key, vt, orm);

    // final projection — d_out is FP32 (reference output dtype float32)
    gemm_out_kernel<<<dim3(8, 64), 256, 0, stream>>>(orm, wt_o, bob, (float*)d_out);
}

// Round 8
// 512.862 us; speedup vs baseline: 1.3335x; 1.3335x over previous
//
#include <hip/hip_runtime.h>
#include <hip/hip_bf16.h>

// Problem constants
#define B_ 4
#define T_ 2048
#define E_ 1024
#define H_ 16
#define D_ 64
#define M_ (B_ * T_)  // 8192 rows

typedef unsigned short u16;
typedef short s16x8 __attribute__((ext_vector_type(8)));
typedef unsigned short u16x8 __attribute__((ext_vector_type(8)));
typedef float f32x4 __attribute__((ext_vector_type(4)));

__device__ __forceinline__ u16 f2bf(float f) {
    __hip_bfloat16 h = __float2bfloat16(f);
    return __builtin_bit_cast(u16, h);
}
__device__ __forceinline__ float bf2f(u16 u) {
    unsigned int v = ((unsigned int)u) << 16;
    return __builtin_bit_cast(float, v);
}

// ---------------------------------------------------------------------------
// Dtype probe (block-cooperative, 256 threads). Inputs verified bf16
// behaviorally (rounds 2-6); fp32 path kept for robustness.
// ---------------------------------------------------------------------------
__device__ __forceinline__ int block_probe_is_bf16(const void* x, int tid) {
    const u16* p = (const u16*)x;
    u16 u = p[tid];
    int e = (u >> 7) & 0xFF;
    int ok = ((u & 0x7FFF) == 0 || (e >= 103 && e <= 133)) ? 1 : 0;
    return (__syncthreads_count(ok) >= 240) ? 1 : 0;
}

// ---------------------------------------------------------------------------
// bf16 transpose for two weight matrices: W[k][n] -> Wt[n][k]
// ---------------------------------------------------------------------------
__global__ __launch_bounds__(256) void transpose_w_single_kernel(
    const void* __restrict__ w0, const void* __restrict__ w1,
    u16* __restrict__ o0, u16* __restrict__ o1,
    const void* __restrict__ xprobe)
{
    __shared__ u16 th[64][66];
    const int x = threadIdx.x, y = threadIdx.y;
    const int isbf = block_probe_is_bf16(xprobe, y * 64 + x);
    const void* in = blockIdx.z ? w1 : w0;
    u16* o = blockIdx.z ? o1 : o0;
    const int r0 = blockIdx.y * 64;
    const int c0 = blockIdx.x * 64;
    #pragma unroll
    for (int j = 0; j < 16; j++) {
        const size_t idx = (size_t)(r0 + y * 16 + j) * E_ + c0 + x;
        float v = isbf ? bf2f(((const u16*)in)[idx]) : ((const float*)in)[idx];
        th[y * 16 + j][x] = f2bf(v);
    }
    __syncthreads();
    #pragma unroll
    for (int j = 0; j < 16; j++)
        o[(size_t)(c0 + y * 16 + j) * E_ + r0 + x] = th[x][y * 16 + j];
}

// ---------------------------------------------------------------------------
// All four biases -> fp32 (bq|bk|bv|bo)
// ---------------------------------------------------------------------------
__global__ __launch_bounds__(256) void convert_bias_kernel(
    const void* __restrict__ bq, const void* __restrict__ bk,
    const void* __restrict__ bv, const void* __restrict__ bo,
    float* __restrict__ outb, const void* __restrict__ xprobe)
{
    const int isbf = block_probe_is_bf16(xprobe, threadIdx.x);
    const int i = blockIdx.x * 256 + threadIdx.x;  // < 1024
    const int w = blockIdx.y;
    const void* p = (w == 0) ? bq : (w == 1) ? bk : (w == 2) ? bv : bo;
    float v = isbf ? bf2f(((const u16*)p)[i]) : ((const float*)p)[i];
    outb[w * 1024 + i] = v;
}

// ---------------------------------------------------------------------------
// Plain bf16 MFMA GEMM, fp32 output: C[row][n] = A[m_base+row][k] @ Bt[n][k]^T
// + bias[n]. A dual-path (a_mode: -1 probe / 1 bf16). 128x128 tile, BK=64.
// ---------------------------------------------------------------------------
__global__ __launch_bounds__(256) void gemm_f32out_kernel(
    const void* __restrict__ A, int a_mode, int m_base,
    const u16* __restrict__ Bt, const float* __restrict__ bias,
    float* __restrict__ Cout)
{
    __shared__ u16 a_lds[128 * 72];
    __shared__ u16 b_lds[128 * 72];
    const int tid = threadIdx.x;
    const int isbf = block_probe_is_bf16(A, tid);
    const int a_bf = (a_mode < 0) ? isbf : a_mode;
    const int wave = tid >> 6, lane = tid & 63;
    const int lane15 = lane & 15, quad = lane >> 4;
    const int wm = (wave & 1) * 64, wn = (wave >> 1) * 64;
    const int m0 = blockIdx.y * 128, n0 = blockIdx.x * 128;
    const int srow = tid >> 1;
    const int soff = (tid & 1) * 32;

    f32x4 acc[4][4];
    #pragma unroll
    for (int i = 0; i < 4; i++)
        #pragma unroll
        for (int j = 0; j < 4; j++) acc[i][j] = (f32x4)0.0f;

    for (int kk = 0; kk < E_; kk += 64) {
        u16x8 av[4];
        if (a_bf) {
            const u16* xa = (const u16*)A + (size_t)(m_base + m0 + srow) * E_ + kk + soff;
            #pragma unroll
            for (int j = 0; j < 4; j++) av[j] = *(const u16x8*)(xa + j * 8);
        } else {
            const float* xa = (const float*)A + (size_t)(m_base + m0 + srow) * E_ + kk + soff;
            #pragma unroll
            for (int j = 0; j < 4; j++) {
                f32x4 t0 = *(const f32x4*)(xa + j * 8);
                f32x4 t1 = *(const f32x4*)(xa + j * 8 + 4);
                u16x8 o;
                #pragma unroll
                for (int e = 0; e < 4; e++) { o[e] = f2bf(t0[e]); o[4 + e] = f2bf(t1[e]); }
                av[j] = o;
            }
        }
        const u16* bp = Bt + (size_t)(n0 + srow) * E_ + kk + soff;
        u16x8 bv[4];
        #pragma unroll
        for (int j = 0; j < 4; j++) bv[j] = *(const u16x8*)(bp + j * 8);

        __syncthreads();
        #pragma unroll
        for (int j = 0; j < 4; j++) {
            *(u16x8*)&a_lds[srow * 72 + soff + j * 8] = av[j];
            *(u16x8*)&b_lds[srow * 72 + soff + j * 8] = bv[j];
        }
        __syncthreads();
        #pragma unroll
        for (int ks = 0; ks < 2; ks++) {
            s16x8 af[4], bfr[4];
            #pragma unroll
            for (int i = 0; i < 4; i++)
                af[i] = *(const s16x8*)&a_lds[(wm + i * 16 + lane15) * 72 + ks * 32 + quad * 8];
            #pragma unroll
            for (int j = 0; j < 4; j++)
                bfr[j] = *(const s16x8*)&b_lds[(wn + j * 16 + lane15) * 72 + ks * 32 + quad * 8];
            #pragma unroll
            for (int i = 0; i < 4; i++)
                #pragma unroll
                for (int j = 0; j < 4; j++)
                    acc[i][j] = __builtin_amdgcn_mfma_f32_16x16x32_bf16(af[i], bfr[j], acc[i][j], 0, 0, 0);
        }
    }

    #pragma unroll
    for (int j = 0; j < 4; j++) {
        const int col = n0 + wn + j * 16 + lane15;
        const float bb = bias[col];
        #pragma unroll
        for (int i = 0; i < 4; i++) {
            const int row = m0 + wm + i * 16 + quad * 4;
            #pragma unroll
            for (int r = 0; r < 4; r++)
                Cout[(size_t)(row + r) * E_ + col] = acc[i][j][r] + bb;
        }
    }
}

// ---------------------------------------------------------------------------
// V projection (bf16 MFMA, A from original X) with FUSED per-head transpose:
// writes vt[(b*16+h)*64+d][t] via an LDS retile epilogue. bias fp32.
// ---------------------------------------------------------------------------
__global__ __launch_bounds__(256) void gemm_v_fused_kernel(
    const void* __restrict__ X, const u16* __restrict__ Bt,
    const float* __restrict__ bias, u16* __restrict__ Vt)
{
    __shared__ u16 smem[2 * 128 * 72];  // a | b, later c_tile[128][132]
    u16* a_lds = smem;
    u16* b_lds = smem + 128 * 72;
    const int tid = threadIdx.x;
    const int isbf = block_probe_is_bf16(X, tid);
    const int wave = tid >> 6, lane = tid & 63;
    const int lane15 = lane & 15, quad = lane >> 4;
    const int wm = (wave & 1) * 64, wn = (wave >> 1) * 64;
    const int m0 = blockIdx.y * 128, n0 = blockIdx.x * 128;
    const int srow = tid >> 1;
    const int soff = (tid & 1) * 32;

    f32x4 acc[4][4];
    #pragma unroll
    for (int i = 0; i < 4; i++)
        #pragma unroll
        for (int j = 0; j < 4; j++) acc[i][j] = (f32x4)0.0f;

    for (int kk = 0; kk < E_; kk += 64) {
        u16x8 av[4];
        if (isbf) {
            const u16* xa = (const u16*)X + (size_t)(m0 + srow) * E_ + kk + soff;
            #pragma unroll
            for (int j = 0; j < 4; j++) av[j] = *(const u16x8*)(xa + j * 8);
        } else {
            const float* xa = (const float*)X + (size_t)(m0 + srow) * E_ + kk + soff;
            #pragma unroll
            for (int j = 0; j < 4; j++) {
                f32x4 t0 = *(const f32x4*)(xa + j * 8);
                f32x4 t1 = *(const f32x4*)(xa + j * 8 + 4);
                u16x8 o;
                #pragma unroll
                for (int e = 0; e < 4; e++) { o[e] = f2bf(t0[e]); o[4 + e] = f2bf(t1[e]); }
                av[j] = o;
            }
        }
        const u16* bp = Bt + (size_t)(n0 + srow) * E_ + kk + soff;
        u16x8 bv[4];
        #pragma unroll
        for (int j = 0; j < 4; j++) bv[j] = *(const u16x8*)(bp + j * 8);

        __syncthreads();
        #pragma unroll
        for (int j = 0; j < 4; j++) {
            *(u16x8*)&a_lds[srow * 72 + soff + j * 8] = av[j];
            *(u16x8*)&b_lds[srow * 72 + soff + j * 8] = bv[j];
        }
        __syncthreads();
        #pragma unroll
        for (int ks = 0; ks < 2; ks++) {
            s16x8 af[4], bfr[4];
            #pragma unroll
            for (int i = 0; i < 4; i++)
                af[i] = *(const s16x8*)&a_lds[(wm + i * 16 + lane15) * 72 + ks * 32 + quad * 8];
            #pragma unroll
            for (int j = 0; j < 4; j++)
                bfr[j] = *(const s16x8*)&b_lds[(wn + j * 16 + lane15) * 72 + ks * 32 + quad * 8];
            #pragma unroll
            for (int i = 0; i < 4; i++)
                #pragma unroll
                for (int j = 0; j < 4; j++)
                    acc[i][j] = __builtin_amdgcn_mfma_f32_16x16x32_bf16(af[i], bfr[j], acc[i][j], 0, 0, 0);
        }
    }

    // epilogue: C tile -> LDS -> transposed coalesced store into Vt
    __syncthreads();
    u16* c_tile = smem;  // [128][132]
    #pragma unroll
    for (int j = 0; j < 4; j++) {
        const float bb = bias[n0 + wn + j * 16 + lane15];
        #pragma unroll
        for (int i = 0; i < 4; i++)
            #pragma unroll
            for (int r = 0; r < 4; r++)
                c_tile[(wm + i * 16 + quad * 4 + r) * 132 + wn + j * 16 + lane15] =
                    f2bf(acc[i][j][r] + bb);
    }
    __syncthreads();
    const int b = m0 >> 11, t0 = m0 & 2047;
    const int orow = tid >> 1, half = tid & 1;
    u16* dst = Vt + ((size_t)b * 1024 + n0 + orow) * T_ + t0 + half * 64;
    #pragma unroll
    for (int c = 0; c < 8; c++) {
        u16x8 o;
        #pragma unroll
        for (int e = 0; e < 8; e++)
            o[e] = c_tile[(half * 64 + c * 8 + e) * 132 + orow];
        *(u16x8*)(dst + c * 8) = o;
    }
}

// ---------------------------------------------------------------------------
// quantum_layer: out[row][:] = cumprod(cos(in[row][:])), 1024 features.
// ---------------------------------------------------------------------------
__global__ __launch_bounds__(256) void quantum_kernel(
    const float* __restrict__ in, u16* __restrict__ out)
{
    const int wave = threadIdx.x >> 6, lane = threadIdx.x & 63;
    const size_t row = (size_t)blockIdx.x * 4 + wave;
    const float* p = in + row * E_ + lane * 16;
    float v[16];
    #pragma unroll
    for (int j = 0; j < 16; j += 4) {
        f32x4 t = *(const f32x4*)(p + j);
        v[j] = t[0]; v[j + 1] = t[1]; v[j + 2] = t[2]; v[j + 3] = t[3];
    }
    float pl[16];
    float run = 1.0f;
    #pragma unroll
    for (int j = 0; j < 16; j++) { run *= cosf(v[j]); pl[j] = run; }
    float incl = run;
    #pragma unroll
    for (int off = 1; off < 64; off <<= 1) {
        float t = __shfl_up(incl, off);
        if (lane >= off) incl *= t;
    }
    float pref = __shfl_up(incl, 1);
    if (lane == 0) pref = 1.0f;
    u16x8 o0, o1;
    #pragma unroll
    for (int j = 0; j < 8; j++) {
        o0[j] = f2bf(pref * pl[j]);
        o1[j] = f2bf(pref * pl[j + 8]);
    }
    *(u16x8*)(out + row * E_ + lane * 16) = o0;
    *(u16x8*)(out + row * E_ + lane * 16 + 8) = o1;
}

// ---------------------------------------------------------------------------
// MFMA flash attention — NO-MAX softmax.
// Safe because q,k in [-1,1]^64 -> |score*0.125| <= 8 -> exp <= 2981,
// row-sum <= 6.1e6: no fp32 overflow possible. Eliminates the running max,
// alpha rescaling, and all in-loop shuffles. Q prescaled by 0.125 (exact
// power-of-2 in bf16) during staging.
// ---------------------------------------------------------------------------
__global__ __launch_bounds__(256) void attn_kernel(
    const u16* __restrict__ Qrm, const u16* __restrict__ Krm,
    const u16* __restrict__ Vt, u16* __restrict__ Orm)
{
    __shared__ u16 q_lds[128 * 72];
    __shared__ u16 kp_lds[128 * 72];  // K chunk [64][72], then P [128][72]
    __shared__ u16 v_lds[64 * 72];
    const int tid = threadIdx.x;
    const int wave = tid >> 6, lane = tid & 63;
    const int lane15 = lane & 15, quad = lane >> 4;
    const int bh = blockIdx.y;
    const int b = bh >> 4, h = bh & 15;
    const int t0 = blockIdx.x * 128;

    {   // stage Q tile once, prescaled by 1/8 (exact in bf16)
        const int srow = tid >> 1;
        const int soff = (tid & 1) * 32;
        const u16* src = Qrm + (size_t)(b * T_ + t0 + srow) * E_ + h * 64 + soff;
        #pragma unroll
        for (int j = 0; j < 4; j++) {
            u16x8 t = *(const u16x8*)(src + j * 8);
            u16x8 o;
            #pragma unroll
            for (int e = 0; e < 8; e++) o[e] = f2bf(bf2f(t[e]) * 0.125f);
            *(u16x8*)&q_lds[srow * 72 + soff + j * 8] = o;
        }
    }

    float lsum[2][4];
    f32x4 oacc[2][4];
    #pragma unroll
    for (int mt = 0; mt < 2; mt++) {
        #pragma unroll
        for (int r = 0; r < 4; r++) lsum[mt][r] = 0.0f;
        #pragma unroll
        for (int n = 0; n < 4; n++) oacc[mt][n] = (f32x4)0.0f;
    }

    const u16* kbase = Krm + (size_t)(b * T_) * E_ + h * 64;
    const u16* vbase = Vt + (size_t)bh * 64 * T_;

    for (int tk0 = 0; tk0 < T_; tk0 += 64) {
        __syncthreads();  // previous chunk's P/V reads done
        {   // stage K chunk [64 tk][64 d] and V^T chunk [64 d][64 tk]
            const int srow = tid >> 2;
            const int soff = (tid & 3) * 16;
            const u16* ksrc = kbase + (size_t)(tk0 + srow) * E_ + soff;
            *(s16x8*)&kp_lds[srow * 72 + soff]     = *(const s16x8*)(ksrc);
            *(s16x8*)&kp_lds[srow * 72 + soff + 8] = *(const s16x8*)(ksrc + 8);
            const u16* vsrc = vbase + (size_t)srow * T_ + tk0 + soff;
            *(s16x8*)&v_lds[srow * 72 + soff]     = *(const s16x8*)(vsrc);
            *(s16x8*)&v_lds[srow * 72 + soff + 8] = *(const s16x8*)(vsrc + 8);
        }
        __syncthreads();

        // S = (Q/8) K^T
        f32x4 sacc[2][4];
        #pragma unroll
        for (int mt = 0; mt < 2; mt++)
            #pragma unroll
            for (int j = 0; j < 4; j++) sacc[mt][j] = (f32x4)0.0f;
        #pragma unroll
        for (int ks = 0; ks < 2; ks++) {
            s16x8 qa[2], kb[4];
            #pragma unroll
            for (int mt = 0; mt < 2; mt++)
                qa[mt] = *(const s16x8*)&q_lds[(wave * 32 + mt * 16 + lane15) * 72 + ks * 32 + quad * 8];
            #pragma unroll
            for (int j = 0; j < 4; j++)
                kb[j] = *(const s16x8*)&kp_lds[(j * 16 + lane15) * 72 + ks * 32 + quad * 8];
            #pragma unroll
            for (int mt = 0; mt < 2; mt++)
                #pragma unroll
                for (int j = 0; j < 4; j++)
                    sacc[mt][j] = __builtin_amdgcn_mfma_f32_16x16x32_bf16(
                        qa[mt], kb[j], sacc[mt][j], 0, 0, 0);
        }

        // P = exp(S) — no max subtraction, no rescale, no shuffles
        #pragma unroll
        for (int mt = 0; mt < 2; mt++)
            #pragma unroll
            for (int j = 0; j < 4; j++)
                #pragma unroll
                for (int r = 0; r < 4; r++) {
                    const float pv = __expf(sacc[mt][j][r]);
                    sacc[mt][j][r] = pv;
                    lsum[mt][r] += pv;
                }

        __syncthreads();  // all waves done reading K before P overwrites it

        // write P (bf16) into kp_lds; each wave owns its 32 rows exclusively
        #pragma unroll
        for (int mt = 0; mt < 2; mt++)
            #pragma unroll
            for (int j = 0; j < 4; j++)
                #pragma unroll
                for (int r = 0; r < 4; r++)
                    kp_lds[(wave * 32 + mt * 16 + quad * 4 + r) * 72 + j * 16 + lane15] =
                        f2bf(sacc[mt][j][r]);

        // O += P V   (same-wave DS ordering: no barrier needed)
        #pragma unroll
        for (int ks = 0; ks < 2; ks++) {
            s16x8 pa[2], vb[4];
            #pragma unroll
            for (int mt = 0; mt < 2; mt++)
                pa[mt] = *(const s16x8*)&kp_lds[(wave * 32 + mt * 16 + lane15) * 72 + ks * 32 + quad * 8];
            #pragma unroll
            for (int n = 0; n < 4; n++)
                vb[n] = *(const s16x8*)&v_lds[(n * 16 + lane15) * 72 + ks * 32 + quad * 8];
            #pragma unroll
            for (int mt = 0; mt < 2; mt++)
                #pragma unroll
                for (int n = 0; n < 4; n++)
                    oacc[mt][n] = __builtin_amdgcn_mfma_f32_16x16x32_bf16(
                        pa[mt], vb[n], oacc[mt][n], 0, 0, 0);
        }
    }

    // epilogue: reduce lsum across the 16 lanes of each quad (cols), normalize
    #pragma unroll
    for (int mt = 0; mt < 2; mt++) {
        #pragma unroll
        for (int r = 0; r < 4; r++) {
            float l = lsum[mt][r];
            #pragma unroll
            for (int d = 1; d < 16; d <<= 1)
                l += __shfl_xor(l, d);
            const float inv = 1.0f / l;
            const size_t row = (size_t)(b * T_ + t0 + wave * 32 + mt * 16 + quad * 4 + r);
            #pragma unroll
            for (int n = 0; n < 4; n++)
                Orm[row * E_ + h * 64 + n * 16 + lane15] = f2bf(oacc[mt][n][r] * inv);
        }
    }
}

// ---------------------------------------------------------------------------
// Workspace layout, peak 77 MiB (known-safe):
//   [0, 2M)   wt_o          [2M,+16K) biasf (4x1024 fp32)
//   [3M, 5M)  wt_q   [7M, 9M) wt_k   [11M,13M) wt_v
//   [13M,29M) vt  (per-head transposed V)
//   [29M,45M) key = quantum(q_proj)   (attention KEY)
//   [45M,61M) qry = quantum(k_proj)   (attention QUERY)
//   [61M,77M) tmp (fp32, 4096 rows) -> later orm (bf16, 8192 rows)
// ---------------------------------------------------------------------------
extern "C" void kernel_launch(void* const* d_in, const int* in_sizes, int n_in,
                              void* d_out, int out_size, void* d_ws, size_t ws_size,
                              hipStream_t stream) {
    (void)in_sizes; (void)n_in; (void)out_size; (void)ws_size;
    const void* x  = d_in[0];
    const void* Wq = d_in[1];
    const void* bq = d_in[2];
    const void* Wk = d_in[3];
    const void* bk = d_in[4];
    const void* Wv = d_in[5];
    const void* bv = d_in[6];
    const void* Wo = d_in[7];
    const void* bo = d_in[8];

    char* ws = (char*)d_ws;
    const size_t MB = 1024 * 1024;
    u16*   wt_o  = (u16*)(ws);
    float* biasf = (float*)(ws + 2 * MB);
    u16*   wt_q  = (u16*)(ws + 3 * MB);
    u16*   wt_k  = (u16*)(ws + 7 * MB);
    u16*   wt_v  = (u16*)(ws + 11 * MB);
    u16*   vt    = (u16*)(ws + 13 * MB);
    u16*   key   = (u16*)(ws + 29 * MB);
    u16*   qry   = (u16*)(ws + 45 * MB);
    float* tmp   = (float*)(ws + 61 * MB);
    u16*   orm   = (u16*)(ws + 61 * MB);

    transpose_w_single_kernel<<<dim3(16, 16, 2), dim3(64, 4), 0, stream>>>(
        Wq, Wk, wt_q, wt_k, x);
    transpose_w_single_kernel<<<dim3(16, 16, 2), dim3(64, 4), 0, stream>>>(
        Wv, Wo, wt_v, wt_o, x);
    convert_bias_kernel<<<dim3(4, 4), 256, 0, stream>>>(
        bq, bk, bv, bo, biasf, x);

    // V projection with fused per-head transpose -> vt
    gemm_v_fused_kernel<<<dim3(8, 64), 256, 0, stream>>>(x, wt_v, biasf + 2 * 1024, vt);

    // q-projection -> quantum -> key  (reference: KEY = quantum(x@Wq+bq))
    for (int hh = 0; hh < 2; hh++) {
        gemm_f32out_kernel<<<dim3(8, 32), 256, 0, stream>>>(
            x, -1, hh * 4096, wt_q, biasf + 0 * 1024, tmp);
        quantum_kernel<<<1024, 256, 0, stream>>>(tmp, key + (size_t)hh * 4096 * E_);
    }
    // k-projection -> quantum -> qry  (reference: QUERY = quantum(x@Wk+bk))
    for (int hh = 0; hh < 2; hh++) {
        gemm_f32out_kernel<<<dim3(8, 32), 256, 0, stream>>>(
            x, -1, hh * 4096, wt_k, biasf + 1 * 1024, tmp);
        quantum_kernel<<<1024, 256, 0, stream>>>(tmp, qry + (size_t)hh * 4096 * E_);
    }

    attn_kernel<<<dim3(16, 64), 256, 0, stream>>>(qry, key, vt, orm);

    // final projection — d_out is fp32
    gemm_f32out_kernel<<<dim3(8, 64), 256, 0, stream>>>(
        orm, 1, 0, wt_o, biasf + 3 * 1024, (float*)d_out);
}